// Round 5
// baseline (1373.304 us; speedup 1.0000x reference)
//
#include <hip/hip_runtime.h>
#include <stdint.h>

// ---------------------------------------------------------------------------
// GraphConvLayer fused pipeline (round 5 = round-3/4 MFMA kernel, resubmitted
// unchanged after repeated GPU capacity timeouts; fragment layouts & swizzle
// re-audited twice off-line).
//
// N=100000 nodes, E=800000 edges, dims 64, H=8 heads (HD=8).
//
// Factorizations:
//  * u = A[src] + (B[dst]+b1) + ea@W1c    (A,B per-node tables, bf16)
//  * msum[d] = (sum gelu(u)) @ msg_w2 + cnt[d]*msg_b2   (W2 applied per-node)
//  * softmax weight is per-dst -> applied per-node in K5
//  * only LAST edge per dst contributes attention -> k_win resolves winners,
//    k2b computes ~N winner logits via MFMA.
//
// Error budget: softmax is over the global node axis (~100k rows, logit
// sigma~0.5) so every attention weight <= ~1.3e-4; the whole message path is
// scaled by it. bf16 tables/ea and sigmoid-GELU in k2 are safe (<=1e-5 final).
//
// k2 MFMA: U^T[n][e] per 64-edge tile; A-frags = W1c^T static in registers;
// B-frags = ea tile in LDS bf16, XOR-swizzled (byte ^= (row&7)<<4) to kill
// the bank conflicts of 128B rows on ds_read_b128 (audited: 8 acc/bank/wave
// on both write and read sides = throughput-minimal).
//
// ws layout (bytes): P:N*512 | gsum:N*256 @N*512 | attn:N*32 @N*768 |
//   cnt:N*4 @N*800 | last:N*4 @N*804 | partial @N*808 (NPART*64) | hms (+64)
// ---------------------------------------------------------------------------

#define TPB 256
#define NPART 256

typedef short short8v __attribute__((ext_vector_type(8)));
typedef float float4v __attribute__((ext_vector_type(4)));
typedef unsigned short ushort4v __attribute__((ext_vector_type(4)));

static __device__ __forceinline__ float bf2f(unsigned short u) {
  union { uint32_t i; float f; } v; v.i = ((uint32_t)u) << 16; return v.f;
}
static __device__ __forceinline__ unsigned short f2bf(float f) {
  uint32_t x = __float_as_uint(f);
  return (unsigned short)((x + 0x7fffu + ((x >> 16) & 1u)) >> 16);
}
static __device__ __forceinline__ float bcastf(float v, int k) {
  return __uint_as_float((uint32_t)__builtin_amdgcn_readlane((int)__float_as_uint(v), k));
}
static __device__ __forceinline__ float gelu_exact(float x) {
  return 0.5f * x * (1.0f + erff(x * 0.70710678118654752440f));
}
static __device__ __forceinline__ void sm_merge(float& m, float& s, float mo, float so) {
  float M = fmaxf(m, mo);
  float sn = 0.0f;
  if (m > -INFINITY) sn += s * expf(m - M);
  if (mo > -INFINITY) sn += so * expf(mo - M);
  m = M; s = sn;
}

// ---------------------------------------------------------------------------
// K0: init gsum=0, attn=-inf, cnt=0, last=-1
__global__ __launch_bounds__(TPB) void k0_init(float* __restrict__ gsum,
                                               float* __restrict__ attn,
                                               float* __restrict__ cnt,
                                               int* __restrict__ last, int N) {
  int i = blockIdx.x * TPB + threadIdx.x;
  if (i < N * 64) gsum[i] = 0.0f;
  if (i < N * 8) attn[i] = -INFINITY;
  if (i < N) { cnt[i] = 0.0f; last[i] = -1; }
}

// ---------------------------------------------------------------------------
// Kw: winner resolve (last edge per dst) + in-degree count
__global__ __launch_bounds__(TPB) void k_win(const int* __restrict__ ei,
                                             int* __restrict__ last,
                                             float* __restrict__ cnt, int E) {
  int e = blockIdx.x * TPB + threadIdx.x;
  if (e < E) {
    int d = ei[E + e];
    atomicMax(&last[d], e);
    __hip_atomic_fetch_add(&cnt[d], 1.0f, __ATOMIC_RELAXED,
                           __HIP_MEMORY_SCOPE_AGENT);
  }
}

// ---------------------------------------------------------------------------
// K1: per-node tables: P[n] = [x@W1a | x@W1b+msg_b1 | x@q_w+q_b | x@kv_wA+kv_b]
__global__ __launch_bounds__(TPB) void k1_node(
    const float* __restrict__ x,
    const float* __restrict__ msg_w1, const float* __restrict__ msg_b1,
    const float* __restrict__ q_w, const float* __restrict__ q_b,
    const float* __restrict__ kv_w, const float* __restrict__ kv_b,
    unsigned short* __restrict__ P, int N) {
  __shared__ unsigned short Wc[64][256];  // bf16 combined weights, 32 KB
  __shared__ float bc[256];
  __shared__ float xs[16][64];
  int t = threadIdx.x;
  for (int idx = t; idx < 64 * 256; idx += TPB) {
    int k = idx >> 8, j = idx & 255;
    float w;
    if (j < 64)       w = msg_w1[k * 64 + j];
    else if (j < 128) w = msg_w1[(64 + k) * 64 + (j - 64)];
    else if (j < 192) w = q_w[k * 64 + (j - 128)];
    else              w = kv_w[k * 64 + (j - 192)];
    Wc[k][j] = f2bf(w);
  }
  {
    int j = t;
    bc[j] = (j < 64) ? 0.0f
          : (j < 128) ? msg_b1[j - 64]
          : (j < 192) ? q_b[j - 128] : kv_b[j - 192];
  }
  __syncthreads();
  int c0 = t & 63;
  int r0 = (t >> 6) * 4;
  int nchunks = N >> 4;  // 100000 = 16 * 6250
  for (int chunk = blockIdx.x; chunk < nchunks; chunk += gridDim.x) {
    int base = chunk * 16;
    #pragma unroll
    for (int i = 0; i < 4; ++i) {
      int idx = i * TPB + t;
      xs[idx >> 6][idx & 63] = x[(size_t)base * 64 + idx];
    }
    __syncthreads();
    float acc[4][4];
    #pragma unroll
    for (int r = 0; r < 4; ++r)
      #pragma unroll
      for (int c = 0; c < 4; ++c) acc[r][c] = bc[c0 + 64 * c];
    #pragma unroll
    for (int k = 0; k < 64; ++k) {
      float w0 = bf2f(Wc[k][c0]);
      float w1 = bf2f(Wc[k][c0 + 64]);
      float w2 = bf2f(Wc[k][c0 + 128]);
      float w3 = bf2f(Wc[k][c0 + 192]);
      #pragma unroll
      for (int r = 0; r < 4; ++r) {
        float xv = xs[r0 + r][k];
        acc[r][0] = fmaf(xv, w0, acc[r][0]);
        acc[r][1] = fmaf(xv, w1, acc[r][1]);
        acc[r][2] = fmaf(xv, w2, acc[r][2]);
        acc[r][3] = fmaf(xv, w3, acc[r][3]);
      }
    }
    #pragma unroll
    for (int r = 0; r < 4; ++r)
      #pragma unroll
      for (int c = 0; c < 4; ++c)
        P[(size_t)(base + r0 + r) * 256 + c0 + 64 * c] = f2bf(acc[r][c]);
    __syncthreads();
  }
}

// ---------------------------------------------------------------------------
// K2: per-edge MFMA kernel. Block = 4 waves, 64 edges per tile (16 per wave).
//   Uc^T = W1c^T @ ea^T via mfma_f32_16x16x32_bf16;
//   u = Uc + A[s] + B[d];  gsum[d] += fast_gelu(u)
__global__ __launch_bounds__(TPB) void k2_edge(
    const float* __restrict__ ea, const int* __restrict__ ei,
    const unsigned short* __restrict__ P, float* __restrict__ gsum,
    const float* __restrict__ msg_w1, int N, int E) {
  __shared__ unsigned short eat[64 * 64];  // bf16 ea tile, swizzled, 8 KB
  int t = threadIdx.x;
  int lane = t & 63, wave = t >> 6;
  int n0 = lane & 15, kg = lane >> 4;
  // A-fragments: W1c^T, lane l supplies A[a*16+(l&15)][s*32+(l>>4)*8+i]
  short8v af[4][2];
  #pragma unroll
  for (int a = 0; a < 4; ++a)
    #pragma unroll
    for (int s = 0; s < 2; ++s)
      #pragma unroll
      for (int i = 0; i < 8; ++i) {
        int k = s * 32 + kg * 8 + i;
        af[a][s][i] = (short)f2bf(msg_w1[(size_t)(128 + k) * 64 + a * 16 + n0]);
      }
  int row = t >> 2, q = t & 3;  // staging map: row=edge-in-tile, q=16-col group
  int erow = (wave << 4) + n0;  // edge-in-tile this lane assembles
  int ntiles = E >> 6;          // 12500
  for (int tile = blockIdx.x; tile < ntiles; tile += gridDim.x) {
    int ebase = tile << 6;
    __syncthreads();  // previous tile's reads done before overwrite
    {
      const float4v* src4 = (const float4v*)(ea + ((size_t)ebase + row) * 64 + q * 16);
      float4v f0 = src4[0], f1 = src4[1], f2 = src4[2], f3 = src4[3];
      short8v v0, v1;
      #pragma unroll
      for (int j = 0; j < 4; ++j) {
        v0[j] = (short)f2bf(f0[j]); v0[4 + j] = (short)f2bf(f1[j]);
        v1[j] = (short)f2bf(f2[j]); v1[4 + j] = (short)f2bf(f3[j]);
      }
      char* bp = (char*)eat;
      int base = row * 128 + q * 32;
      int sw = (row & 7) << 4;
      *(short8v*)(bp + ((base) ^ sw)) = v0;
      *(short8v*)(bp + ((base + 16) ^ sw)) = v1;
    }
    __syncthreads();
    // MFMA: 4 n-tiles x 2 k-steps
    float4v acc[4];
    #pragma unroll
    for (int a = 0; a < 4; ++a) acc[a] = (float4v){0.f, 0.f, 0.f, 0.f};
    {
      const char* bp = (const char*)eat;
      int rbase = erow * 128;
      int sw = (erow & 7) << 4;
      short8v b0 = *(const short8v*)(bp + ((rbase + kg * 16) ^ sw));
      short8v b1 = *(const short8v*)(bp + ((rbase + 64 + kg * 16) ^ sw));
      #pragma unroll
      for (int a = 0; a < 4; ++a) {
        acc[a] = __builtin_amdgcn_mfma_f32_16x16x32_bf16(af[a][0], b0, acc[a], 0, 0, 0);
        acc[a] = __builtin_amdgcn_mfma_f32_16x16x32_bf16(af[a][1], b1, acc[a], 0, 0, 0);
      }
    }
    // assembly: lane covers edge=ebase+erow, n = a*16 + kg*4 + r
    int e = ebase + erow;
    int si = ei[e], di = ei[E + e];
    const ushort4v* pav = (const ushort4v*)(P + (size_t)si * 256 + (kg << 2));
    const ushort4v* pbv = (const ushort4v*)(P + (size_t)di * 256 + 64 + (kg << 2));
    float* gd = gsum + (size_t)di * 64 + (kg << 2);
    #pragma unroll
    for (int a = 0; a < 4; ++a) {
      ushort4v pa = pav[a * 4];
      ushort4v pb = pbv[a * 4];
      #pragma unroll
      for (int r = 0; r < 4; ++r) {
        float u = acc[a][r] + bf2f(pa[r]) + bf2f(pb[r]);
        // fast gelu (sigmoid form): path is scaled by softmax w <= ~1.3e-4
        float g = u / (1.0f + __expf(-1.702f * u));
        __hip_atomic_fetch_add(&gd[a * 16 + r], g, __ATOMIC_RELAXED,
                               __HIP_MEMORY_SCOPE_AGENT);
      }
    }
  }
}

// ---------------------------------------------------------------------------
// K2b: winner attention. Block = 64 nodes; gather winner-edge ea rows,
//   V^T = KVb^T @ ea^T via MFMA; v = V + KV[s]; attn[d][h] = <q,v>_h / sqrt(8)
__global__ __launch_bounds__(TPB) void k2b_attn(
    const float* __restrict__ ea, const int* __restrict__ ei,
    const int* __restrict__ last, const unsigned short* __restrict__ P,
    const float* __restrict__ kv_w, float* __restrict__ attn, int N, int E) {
  __shared__ unsigned short eat[64 * 64];
  int t = threadIdx.x;
  int lane = t & 63, wave = t >> 6;
  int n0 = lane & 15, kg = lane >> 4;
  short8v af[4][2];  // KVb^T fragments
  #pragma unroll
  for (int a = 0; a < 4; ++a)
    #pragma unroll
    for (int s = 0; s < 2; ++s)
      #pragma unroll
      for (int i = 0; i < 8; ++i) {
        int k = s * 32 + kg * 8 + i;
        af[a][s][i] = (short)f2bf(kv_w[(size_t)(64 + k) * 64 + a * 16 + n0]);
      }
  int row = t >> 2, q = t & 3;
  int nb = blockIdx.x * 64;
  // stage winner ea rows (zero-fill for nodes without in-edges)
  {
    int node = nb + row;
    int e = (node < N) ? last[node] : -1;
    short8v v0 = (short8v){0,0,0,0,0,0,0,0}, v1 = v0;
    if (e >= 0) {
      const float4v* src4 = (const float4v*)(ea + (size_t)e * 64 + q * 16);
      float4v f0 = src4[0], f1 = src4[1], f2 = src4[2], f3 = src4[3];
      #pragma unroll
      for (int j = 0; j < 4; ++j) {
        v0[j] = (short)f2bf(f0[j]); v0[4 + j] = (short)f2bf(f1[j]);
        v1[j] = (short)f2bf(f2[j]); v1[4 + j] = (short)f2bf(f3[j]);
      }
    }
    char* bp = (char*)eat;
    int base = row * 128 + q * 32;
    int sw = (row & 7) << 4;
    *(short8v*)(bp + ((base) ^ sw)) = v0;
    *(short8v*)(bp + ((base + 16) ^ sw)) = v1;
  }
  __syncthreads();
  float4v acc[4];
  #pragma unroll
  for (int a = 0; a < 4; ++a) acc[a] = (float4v){0.f, 0.f, 0.f, 0.f};
  {
    int erow = (wave << 4) + n0;
    const char* bp = (const char*)eat;
    int rbase = erow * 128;
    int sw = (erow & 7) << 4;
    short8v b0 = *(const short8v*)(bp + ((rbase + kg * 16) ^ sw));
    short8v b1 = *(const short8v*)(bp + ((rbase + 64 + kg * 16) ^ sw));
    #pragma unroll
    for (int a = 0; a < 4; ++a) {
      acc[a] = __builtin_amdgcn_mfma_f32_16x16x32_bf16(af[a][0], b0, acc[a], 0, 0, 0);
      acc[a] = __builtin_amdgcn_mfma_f32_16x16x32_bf16(af[a][1], b1, acc[a], 0, 0, 0);
    }
  }
  // assembly: lane's node d = nb + wave*16 + n0; components n = a*16+kg*4+r
  int d = nb + (wave << 4) + n0;
  int we = (d < N) ? last[d] : -1;
  bool valid = (we >= 0);
  int sc = valid ? ei[we] : 0;
  int dc = (d < N) ? d : 0;
  const ushort4v* pqv = (const ushort4v*)(P + (size_t)dc * 256 + 128 + (kg << 2));
  const ushort4v* pvv = (const ushort4v*)(P + (size_t)sc * 256 + 192 + (kg << 2));
  #pragma unroll
  for (int a = 0; a < 4; ++a) {
    ushort4v qv = pqv[a * 4];
    ushort4v vv = pvv[a * 4];
    float p = 0.0f;
    #pragma unroll
    for (int r = 0; r < 4; ++r)
      p += bf2f(qv[r]) * (acc[a][r] + bf2f(vv[r]));
    // kg 0/1 hold halves of head 2a; kg 2/3 hold halves of head 2a+1
    p += __shfl_xor(p, 16);
    if (valid && kg == 0) attn[(size_t)d * 8 + 2 * a] = p * 0.35355339059327376f;
    if (valid && kg == 2) attn[(size_t)d * 8 + 2 * a + 1] = p * 0.35355339059327376f;
  }
}

// ---------------------------------------------------------------------------
// K3a: per-head online-softmax partials over attn [N,8]
__global__ __launch_bounds__(TPB) void k3_partial(const float* __restrict__ attn,
                                                  float* __restrict__ partial,
                                                  int N8) {
  int t = threadIdx.x;
  float m = -INFINITY, s = 0.0f;
  for (int idx = blockIdx.x * TPB + t; idx < N8; idx += NPART * TPB) {
    float a = attn[idx];  // head = idx&7 == t&7
    if (a > -INFINITY) {
      float M = fmaxf(m, a);
      s = s * expf(m - M) + expf(a - M);
      m = M;
    }
  }
  #pragma unroll
  for (int off = 8; off <= 32; off <<= 1) {
    float mo = __shfl_xor(m, off), so = __shfl_xor(s, off);
    sm_merge(m, s, mo, so);
  }
  __shared__ float lm[4][8], ls[4][8];
  if ((t & 63) < 8) { lm[t >> 6][t & 7] = m; ls[t >> 6][t & 7] = s; }
  __syncthreads();
  if (t < 8) {
    for (int wv = 1; wv < 4; ++wv) sm_merge(m, s, lm[wv][t], ls[wv][t]);
    partial[blockIdx.x * 16 + t] = m;
    partial[blockIdx.x * 16 + 8 + t] = s;
  }
}

// K3b: finalize — hms[0:8]=hmax, hms[8:16]=hsum
__global__ __launch_bounds__(TPB) void k3_final(const float* __restrict__ partial,
                                                float* __restrict__ hms) {
  int t = threadIdx.x;
  int h = t & 7;
  float m = -INFINITY, s = 0.0f;
  for (int p = t >> 3; p < NPART; p += 32)
    sm_merge(m, s, partial[p * 16 + h], partial[p * 16 + 8 + h]);
  #pragma unroll
  for (int off = 8; off <= 32; off <<= 1) {
    float mo = __shfl_xor(m, off), so = __shfl_xor(s, off);
    sm_merge(m, s, mo, so);
  }
  __shared__ float lm[4][8], ls[4][8];
  if ((t & 63) < 8) { lm[t >> 6][t & 7] = m; ls[t >> 6][t & 7] = s; }
  __syncthreads();
  if (t < 8) {
    for (int wv = 1; wv < 4; ++wv) sm_merge(m, s, lm[wv][t], ls[wv][t]);
    hms[t] = m;
    hms[8 + t] = s;
  }
}

// ---------------------------------------------------------------------------
// K5: per-node output:
//   msum = gsum@MW2 + cnt*mb2 ; agg = w(head)*msum
//   h = gelu([x,agg]@W1+b1)@W2+b2 ; out = LN(x+h)*g+b
__global__ __launch_bounds__(TPB) void k5_out(
    const float* __restrict__ x, const float* __restrict__ gsum,
    const float* __restrict__ cnt, const float* __restrict__ attn,
    const float* __restrict__ hms,
    const float* __restrict__ msg_w2, const float* __restrict__ msg_b2,
    const float* __restrict__ out_w1, const float* __restrict__ out_b1,
    const float* __restrict__ out_w2, const float* __restrict__ out_b2,
    const float* __restrict__ ln_g, const float* __restrict__ ln_b,
    float* __restrict__ out, int N) {
  __shared__ float W1[128][64];   // 32 KB
  __shared__ float W2[64][64];    // 16 KB
  __shared__ float MW2[64][64];   // 16 KB
  int t = threadIdx.x;
  for (int idx = t; idx < 128 * 64; idx += TPB) W1[idx >> 6][idx & 63] = out_w1[idx];
  for (int idx = t; idx < 64 * 64; idx += TPB) {
    W2[idx >> 6][idx & 63] = out_w2[idx];
    MW2[idx >> 6][idx & 63] = msg_w2[idx];
  }
  __syncthreads();
  int lane = t & 63, wave = t >> 6;
  float b1 = out_b1[lane], b2 = out_b2[lane], mb2 = msg_b2[lane];
  float lg = ln_g[lane], lb = ln_b[lane];
  float hm = hms[lane >> 3];
  float rs = 1.0f / hms[8 + (lane >> 3)];
  int ngroups = N >> 2;  // N divisible by 4
  for (int gid = blockIdx.x * 4 + wave; gid < ngroups; gid += gridDim.x * 4) {
    int n0 = gid * 4;
    float xr[4], g[4], msv[4];
    #pragma unroll
    for (int i = 0; i < 4; ++i) {
      int n = n0 + i;
      xr[i] = x[(size_t)n * 64 + lane];
      g[i] = gsum[(size_t)n * 64 + lane];
      msv[i] = cnt[n] * mb2;
    }
    #pragma unroll
    for (int k = 0; k < 64; ++k) {
      float w = MW2[k][lane];
      #pragma unroll
      for (int i = 0; i < 4; ++i) msv[i] = fmaf(bcastf(g[i], k), w, msv[i]);
    }
    float agg[4];
    #pragma unroll
    for (int i = 0; i < 4; ++i) {
      float a = attn[(size_t)(n0 + i) * 8 + (lane >> 3)];
      float wgt = expf(a - hm) * rs;  // exp(-inf)=0 for isolated nodes
      agg[i] = wgt * msv[i];
    }
    float t1[4] = {b1, b1, b1, b1};
    #pragma unroll
    for (int k = 0; k < 64; ++k) {
      float w0 = W1[k][lane];
      #pragma unroll
      for (int i = 0; i < 4; ++i) t1[i] = fmaf(bcastf(xr[i], k), w0, t1[i]);
    }
    #pragma unroll
    for (int k = 0; k < 64; ++k) {
      float w0 = W1[64 + k][lane];
      #pragma unroll
      for (int i = 0; i < 4; ++i) t1[i] = fmaf(bcastf(agg[i], k), w0, t1[i]);
    }
    #pragma unroll
    for (int i = 0; i < 4; ++i) t1[i] = gelu_exact(t1[i]);
    float hh[4] = {b2, b2, b2, b2};
    #pragma unroll
    for (int k = 0; k < 64; ++k) {
      float w0 = W2[k][lane];
      #pragma unroll
      for (int i = 0; i < 4; ++i) hh[i] = fmaf(bcastf(t1[i], k), w0, hh[i]);
    }
    #pragma unroll
    for (int i = 0; i < 4; ++i) {
      float y = xr[i] + hh[i];
      float s = y;
      #pragma unroll
      for (int off = 32; off >= 1; off >>= 1) s += __shfl_xor(s, off);
      float mu = s * (1.0f / 64.0f);
      float c = y - mu;
      float s2 = c * c;
      #pragma unroll
      for (int off = 32; off >= 1; off >>= 1) s2 += __shfl_xor(s2, off);
      float var = s2 * (1.0f / 64.0f);
      out[(size_t)(n0 + i) * 64 + lane] = c * rsqrtf(var + 1e-5f) * lg + lb;
    }
  }
}

// ---------------------------------------------------------------------------
extern "C" void kernel_launch(void* const* d_in, const int* in_sizes, int n_in,
                              void* d_out, int out_size, void* d_ws, size_t ws_size,
                              hipStream_t stream) {
  const float* x       = (const float*)d_in[0];
  const int*   ei      = (const int*)d_in[1];
  const float* ea      = (const float*)d_in[2];
  const float* msg_w1  = (const float*)d_in[3];
  const float* msg_b1  = (const float*)d_in[4];
  const float* msg_w2  = (const float*)d_in[5];
  const float* msg_b2  = (const float*)d_in[6];
  const float* q_w     = (const float*)d_in[7];
  const float* q_b     = (const float*)d_in[8];
  const float* kv_w    = (const float*)d_in[9];
  const float* kv_b    = (const float*)d_in[10];
  const float* out_w1  = (const float*)d_in[11];
  const float* out_b1  = (const float*)d_in[12];
  const float* out_w2  = (const float*)d_in[13];
  const float* out_b2  = (const float*)d_in[14];
  const float* ln_g    = (const float*)d_in[15];
  const float* ln_b    = (const float*)d_in[16];

  int N = in_sizes[0] / 64;
  int E = in_sizes[2] / 64;

  char* ws = (char*)d_ws;
  unsigned short* P = (unsigned short*)ws;                       // N*512 B
  float* gsum = (float*)(ws + (size_t)N * 512);                  // N*256 B
  float* attn = (float*)(ws + (size_t)N * 768);                  // N*32 B
  float* cnt  = (float*)(ws + (size_t)N * 800);                  // N*4 B
  int*   last = (int*)(ws + (size_t)N * 804);                    // N*4 B
  float* partial = (float*)(ws + (size_t)N * 808);               // NPART*64 B
  float* hms  = (float*)(ws + (size_t)N * 808 + NPART * 64);     // 64 B

  float* outp = (float*)d_out;

  k0_init<<<(N * 64 + TPB - 1) / TPB, TPB, 0, stream>>>(gsum, attn, cnt, last, N);
  k_win<<<(E + TPB - 1) / TPB, TPB, 0, stream>>>(ei, last, cnt, E);
  k1_node<<<1024, TPB, 0, stream>>>(x, msg_w1, msg_b1, q_w, q_b, kv_w, kv_b, P, N);
  k2_edge<<<2048, TPB, 0, stream>>>(ea, ei, P, gsum, msg_w1, N, E);
  k2b_attn<<<(N + 63) / 64, TPB, 0, stream>>>(ea, ei, last, P, kv_w, attn, N, E);
  k3_partial<<<NPART, TPB, 0, stream>>>(attn, partial, N * 8);
  k3_final<<<1, TPB, 0, stream>>>(partial, hms);
  k5_out<<<2048, TPB, 0, stream>>>(x, gsum, cnt, attn, hms,
                                   msg_w2, msg_b2, out_w1, out_b1,
                                   out_w2, out_b2, ln_g, ln_b, outp, N);
}

// Round 8
// 876.169 us; speedup vs baseline: 1.5674x; 1.5674x over previous
//
#include <hip/hip_runtime.h>
#include <stdint.h>

// ---------------------------------------------------------------------------
// GraphConvLayer fused pipeline (round 8 = round-6/7 kernel, resubmitted after
// repeated GPU capacity timeouts; alignment & coalescing re-audited off-line).
//
// Round-5 post-mortem: transposed MFMA output (lane=edge) scattered the
// gsum atomics -> 819 MB HBM writes (16 B/atomic), VALUBusy 5.7%. Fix:
// compute C[e][n] = ea @ W1c (operand swap; fragment contents identical),
// so lane holds channels a*16+n0 of edge kg*4+r and each atomic instruction
// writes 16-lane-contiguous 64B runs (round-2-style coalescing).
//
// P-table sections A,B are stored PERMUTED within their 64 channels:
// perm(c) = (c&15)*4 + (c>>4), so a lane's channels {n0,16+n0,32+n0,48+n0}
// sit at ushort offsets n0*4..n0*4+3 (one 8B gather per table per edge).
// Sections Q,KV unpermuted (k2b unchanged).
//
// ws layout (bytes): P:N*512 | gsum:N*256 @N*512 | attn:N*32 @N*768 |
//   cnt:N*4 @N*800 | last:N*4 @N*804 | partial @N*808 (NPART*64) | hms (+64)
// ---------------------------------------------------------------------------

#define TPB 256
#define NPART 256

typedef short short8v __attribute__((ext_vector_type(8)));
typedef float float4v __attribute__((ext_vector_type(4)));
typedef unsigned short ushort4v __attribute__((ext_vector_type(4)));
typedef int int4v __attribute__((ext_vector_type(4)));

static __device__ __forceinline__ float bf2f(unsigned short u) {
  union { uint32_t i; float f; } v; v.i = ((uint32_t)u) << 16; return v.f;
}
static __device__ __forceinline__ unsigned short f2bf(float f) {
  uint32_t x = __float_as_uint(f);
  return (unsigned short)((x + 0x7fffu + ((x >> 16) & 1u)) >> 16);
}
static __device__ __forceinline__ float bcastf(float v, int k) {
  return __uint_as_float((uint32_t)__builtin_amdgcn_readlane((int)__float_as_uint(v), k));
}
static __device__ __forceinline__ float gelu_exact(float x) {
  return 0.5f * x * (1.0f + erff(x * 0.70710678118654752440f));
}
static __device__ __forceinline__ void sm_merge(float& m, float& s, float mo, float so) {
  float M = fmaxf(m, mo);
  float sn = 0.0f;
  if (m > -INFINITY) sn += s * expf(m - M);
  if (mo > -INFINITY) sn += so * expf(mo - M);
  m = M; s = sn;
}

// ---------------------------------------------------------------------------
// K0: init gsum=0, attn=-inf, cnt=0, last=-1
__global__ __launch_bounds__(TPB) void k0_init(float* __restrict__ gsum,
                                               float* __restrict__ attn,
                                               float* __restrict__ cnt,
                                               int* __restrict__ last, int N) {
  int i = blockIdx.x * TPB + threadIdx.x;
  if (i < N * 64) gsum[i] = 0.0f;
  if (i < N * 8) attn[i] = -INFINITY;
  if (i < N) { cnt[i] = 0.0f; last[i] = -1; }
}

// ---------------------------------------------------------------------------
// Kw: winner resolve (last edge per dst) + in-degree count
__global__ __launch_bounds__(TPB) void k_win(const int* __restrict__ ei,
                                             int* __restrict__ last,
                                             float* __restrict__ cnt, int E) {
  int e = blockIdx.x * TPB + threadIdx.x;
  if (e < E) {
    int d = ei[E + e];
    atomicMax(&last[d], e);
    __hip_atomic_fetch_add(&cnt[d], 1.0f, __ATOMIC_RELAXED,
                           __HIP_MEMORY_SCOPE_AGENT);
  }
}

// ---------------------------------------------------------------------------
// K1: per-node tables. Sections 0,1 (A, B+msg_b1) stored channel-permuted
// (perm(c) = (c&15)*4 + (c>>4)); sections 2,3 (Q+q_b, KV+kv_b) standard.
__global__ __launch_bounds__(TPB) void k1_node(
    const float* __restrict__ x,
    const float* __restrict__ msg_w1, const float* __restrict__ msg_b1,
    const float* __restrict__ q_w, const float* __restrict__ q_b,
    const float* __restrict__ kv_w, const float* __restrict__ kv_b,
    unsigned short* __restrict__ P, int N) {
  __shared__ unsigned short Wc[64][256];  // bf16 combined weights, 32 KB
  __shared__ float bc[256];
  __shared__ float xs[16][64];
  int t = threadIdx.x;
  for (int idx = t; idx < 64 * 256; idx += TPB) {
    int k = idx >> 8, j = idx & 255;
    float w;
    if (j < 64)       w = msg_w1[k * 64 + j];
    else if (j < 128) w = msg_w1[(64 + k) * 64 + (j - 64)];
    else if (j < 192) w = q_w[k * 64 + (j - 128)];
    else              w = kv_w[k * 64 + (j - 192)];
    Wc[k][j] = f2bf(w);
  }
  {
    int j = t;
    bc[j] = (j < 64) ? 0.0f
          : (j < 128) ? msg_b1[j - 64]
          : (j < 192) ? q_b[j - 128] : kv_b[j - 192];
  }
  __syncthreads();
  int c0 = t & 63;
  int r0 = (t >> 6) * 4;
  int pcol = (c0 & 15) * 4 + (c0 >> 4);  // permuted column for sections 0,1
  int nchunks = N >> 4;  // 100000 = 16 * 6250
  for (int chunk = blockIdx.x; chunk < nchunks; chunk += gridDim.x) {
    int base = chunk * 16;
    #pragma unroll
    for (int i = 0; i < 4; ++i) {
      int idx = i * TPB + t;
      xs[idx >> 6][idx & 63] = x[(size_t)base * 64 + idx];
    }
    __syncthreads();
    float acc[4][4];
    #pragma unroll
    for (int r = 0; r < 4; ++r)
      #pragma unroll
      for (int c = 0; c < 4; ++c) acc[r][c] = bc[c0 + 64 * c];
    #pragma unroll
    for (int k = 0; k < 64; ++k) {
      float w0 = bf2f(Wc[k][c0]);
      float w1 = bf2f(Wc[k][c0 + 64]);
      float w2 = bf2f(Wc[k][c0 + 128]);
      float w3 = bf2f(Wc[k][c0 + 192]);
      #pragma unroll
      for (int r = 0; r < 4; ++r) {
        float xv = xs[r0 + r][k];
        acc[r][0] = fmaf(xv, w0, acc[r][0]);
        acc[r][1] = fmaf(xv, w1, acc[r][1]);
        acc[r][2] = fmaf(xv, w2, acc[r][2]);
        acc[r][3] = fmaf(xv, w3, acc[r][3]);
      }
    }
    #pragma unroll
    for (int r = 0; r < 4; ++r)
      #pragma unroll
      for (int c = 0; c < 4; ++c) {
        int col = (c < 2) ? pcol : c0;
        P[(size_t)(base + r0 + r) * 256 + 64 * c + col] = f2bf(acc[r][c]);
      }
    __syncthreads();
  }
}

// ---------------------------------------------------------------------------
// K2: per-edge MFMA kernel. Block = 4 waves, 64 edges per tile (16 per wave).
//   C[e][n] = ea @ W1c via mfma_f32_16x16x32_bf16 (A = ea from LDS,
//   B = W1c n-tiles in registers). Lane holds edges kg*4+r, chans a*16+n0.
//   u = C + A[s] + B[d];  gsum[d] += fast_gelu(u)  -- atomics 16-lane
//   contiguous (64B runs).
__global__ __launch_bounds__(TPB) void k2_edge(
    const float* __restrict__ ea, const int* __restrict__ ei,
    const unsigned short* __restrict__ P, float* __restrict__ gsum,
    const float* __restrict__ msg_w1, int N, int E) {
  __shared__ unsigned short eat[64 * 64];  // bf16 ea tile, swizzled, 8 KB
  int t = threadIdx.x;
  int lane = t & 63, wave = t >> 6;
  int n0 = lane & 15, kg = lane >> 4;
  // B-fragments: W1c, lane l supplies B[k=(l>>4)*8+i+32s][n=a*16+(l&15)]
  short8v wf[4][2];
  #pragma unroll
  for (int a = 0; a < 4; ++a)
    #pragma unroll
    for (int s = 0; s < 2; ++s)
      #pragma unroll
      for (int i = 0; i < 8; ++i) {
        int k = s * 32 + kg * 8 + i;
        wf[a][s][i] = (short)f2bf(msg_w1[(size_t)(128 + k) * 64 + a * 16 + n0]);
      }
  int row = t >> 2, q = t & 3;  // staging map: row=edge-in-tile, q=16-col group
  int arow = (wave << 4) + n0;  // edge row this lane reads as A operand
  int ntiles = E >> 6;          // 12500
  for (int tile = blockIdx.x; tile < ntiles; tile += gridDim.x) {
    int ebase = tile << 6;
    __syncthreads();  // previous tile's reads done before overwrite
    {
      const float4v* src4 = (const float4v*)(ea + ((size_t)ebase + row) * 64 + q * 16);
      float4v f0 = src4[0], f1 = src4[1], f2 = src4[2], f3 = src4[3];
      short8v v0, v1;
      #pragma unroll
      for (int j = 0; j < 4; ++j) {
        v0[j] = (short)f2bf(f0[j]); v0[4 + j] = (short)f2bf(f1[j]);
        v1[j] = (short)f2bf(f2[j]); v1[4 + j] = (short)f2bf(f3[j]);
      }
      char* bp = (char*)eat;
      int base = row * 128 + q * 32;
      int sw = (row & 7) << 4;
      *(short8v*)(bp + ((base) ^ sw)) = v0;
      *(short8v*)(bp + ((base + 16) ^ sw)) = v1;
    }
    __syncthreads();
    // MFMA: 4 n-tiles (channels) x 2 k-steps; A = ea rows, B = weight frags
    float4v acc[4];
    #pragma unroll
    for (int a = 0; a < 4; ++a) acc[a] = (float4v){0.f, 0.f, 0.f, 0.f};
    {
      const char* bp = (const char*)eat;
      int rbase = arow * 128;
      int sw = (arow & 7) << 4;
      short8v a0 = *(const short8v*)(bp + ((rbase + kg * 16) ^ sw));
      short8v a1 = *(const short8v*)(bp + ((rbase + 64 + kg * 16) ^ sw));
      #pragma unroll
      for (int a = 0; a < 4; ++a) {
        acc[a] = __builtin_amdgcn_mfma_f32_16x16x32_bf16(a0, wf[a][0], acc[a], 0, 0, 0);
        acc[a] = __builtin_amdgcn_mfma_f32_16x16x32_bf16(a1, wf[a][1], acc[a], 0, 0, 0);
      }
    }
    // assembly: lane covers edges e = ebase + wave*16 + kg*4 + r (r=0..3),
    // channels a*16+n0. Gathers use the permuted P sections (8B per table).
    int e0i = ebase + (wave << 4) + (kg << 2);
    int4v sv = *(const int4v*)(ei + e0i);
    int4v dv = *(const int4v*)(ei + E + e0i);
    #pragma unroll
    for (int r = 0; r < 4; ++r) {
      int si = sv[r], di = dv[r];
      ushort4v pa = *(const ushort4v*)(P + (size_t)si * 256 + (n0 << 2));
      ushort4v pb = *(const ushort4v*)(P + (size_t)di * 256 + 64 + (n0 << 2));
      float* gd = gsum + (size_t)di * 64 + n0;
      #pragma unroll
      for (int a = 0; a < 4; ++a) {
        float u = acc[a][r] + bf2f(pa[a]) + bf2f(pb[a]);
        // fast gelu (sigmoid form): path is scaled by softmax w <= ~1.3e-4
        float g = u / (1.0f + __expf(-1.702f * u));
        __hip_atomic_fetch_add(&gd[a * 16], g, __ATOMIC_RELAXED,
                               __HIP_MEMORY_SCOPE_AGENT);
      }
    }
  }
}

// ---------------------------------------------------------------------------
// K2b: winner attention (unchanged; uses unpermuted P sections 2,3).
__global__ __launch_bounds__(TPB) void k2b_attn(
    const float* __restrict__ ea, const int* __restrict__ ei,
    const int* __restrict__ last, const unsigned short* __restrict__ P,
    const float* __restrict__ kv_w, float* __restrict__ attn, int N, int E) {
  __shared__ unsigned short eat[64 * 64];
  int t = threadIdx.x;
  int lane = t & 63, wave = t >> 6;
  int n0 = lane & 15, kg = lane >> 4;
  short8v af[4][2];  // KVb^T fragments
  #pragma unroll
  for (int a = 0; a < 4; ++a)
    #pragma unroll
    for (int s = 0; s < 2; ++s)
      #pragma unroll
      for (int i = 0; i < 8; ++i) {
        int k = s * 32 + kg * 8 + i;
        af[a][s][i] = (short)f2bf(kv_w[(size_t)(64 + k) * 64 + a * 16 + n0]);
      }
  int row = t >> 2, q = t & 3;
  int nb = blockIdx.x * 64;
  // stage winner ea rows (zero-fill for nodes without in-edges)
  {
    int node = nb + row;
    int e = (node < N) ? last[node] : -1;
    short8v v0 = (short8v){0,0,0,0,0,0,0,0}, v1 = v0;
    if (e >= 0) {
      const float4v* src4 = (const float4v*)(ea + (size_t)e * 64 + q * 16);
      float4v f0 = src4[0], f1 = src4[1], f2 = src4[2], f3 = src4[3];
      #pragma unroll
      for (int j = 0; j < 4; ++j) {
        v0[j] = (short)f2bf(f0[j]); v0[4 + j] = (short)f2bf(f1[j]);
        v1[j] = (short)f2bf(f2[j]); v1[4 + j] = (short)f2bf(f3[j]);
      }
    }
    char* bp = (char*)eat;
    int base = row * 128 + q * 32;
    int sw = (row & 7) << 4;
    *(short8v*)(bp + ((base) ^ sw)) = v0;
    *(short8v*)(bp + ((base + 16) ^ sw)) = v1;
  }
  __syncthreads();
  float4v acc[4];
  #pragma unroll
  for (int a = 0; a < 4; ++a) acc[a] = (float4v){0.f, 0.f, 0.f, 0.f};
  {
    int erow = (wave << 4) + n0;
    const char* bp = (const char*)eat;
    int rbase = erow * 128;
    int sw = (erow & 7) << 4;
    short8v b0 = *(const short8v*)(bp + ((rbase + kg * 16) ^ sw));
    short8v b1 = *(const short8v*)(bp + ((rbase + 64 + kg * 16) ^ sw));
    #pragma unroll
    for (int a = 0; a < 4; ++a) {
      acc[a] = __builtin_amdgcn_mfma_f32_16x16x32_bf16(af[a][0], b0, acc[a], 0, 0, 0);
      acc[a] = __builtin_amdgcn_mfma_f32_16x16x32_bf16(af[a][1], b1, acc[a], 0, 0, 0);
    }
  }
  // assembly: lane's node d = nb + wave*16 + n0; components n = a*16+kg*4+r
  int d = nb + (wave << 4) + n0;
  int we = (d < N) ? last[d] : -1;
  bool valid = (we >= 0);
  int sc = valid ? ei[we] : 0;
  int dc = (d < N) ? d : 0;
  const ushort4v* pqv = (const ushort4v*)(P + (size_t)dc * 256 + 128 + (kg << 2));
  const ushort4v* pvv = (const ushort4v*)(P + (size_t)sc * 256 + 192 + (kg << 2));
  #pragma unroll
  for (int a = 0; a < 4; ++a) {
    ushort4v qv = pqv[a * 4];
    ushort4v vv = pvv[a * 4];
    float p = 0.0f;
    #pragma unroll
    for (int r = 0; r < 4; ++r)
      p += bf2f(qv[r]) * (acc[a][r] + bf2f(vv[r]));
    // kg 0/1 hold halves of head 2a; kg 2/3 hold halves of head 2a+1
    p += __shfl_xor(p, 16);
    if (valid && kg == 0) attn[(size_t)d * 8 + 2 * a] = p * 0.35355339059327376f;
    if (valid && kg == 2) attn[(size_t)d * 8 + 2 * a + 1] = p * 0.35355339059327376f;
  }
}

// ---------------------------------------------------------------------------
// K3a: per-head online-softmax partials over attn [N,8]
__global__ __launch_bounds__(TPB) void k3_partial(const float* __restrict__ attn,
                                                  float* __restrict__ partial,
                                                  int N8) {
  int t = threadIdx.x;
  float m = -INFINITY, s = 0.0f;
  for (int idx = blockIdx.x * TPB + t; idx < N8; idx += NPART * TPB) {
    float a = attn[idx];  // head = idx&7 == t&7
    if (a > -INFINITY) {
      float M = fmaxf(m, a);
      s = s * expf(m - M) + expf(a - M);
      m = M;
    }
  }
  #pragma unroll
  for (int off = 8; off <= 32; off <<= 1) {
    float mo = __shfl_xor(m, off), so = __shfl_xor(s, off);
    sm_merge(m, s, mo, so);
  }
  __shared__ float lm[4][8], ls[4][8];
  if ((t & 63) < 8) { lm[t >> 6][t & 7] = m; ls[t >> 6][t & 7] = s; }
  __syncthreads();
  if (t < 8) {
    for (int wv = 1; wv < 4; ++wv) sm_merge(m, s, lm[wv][t], ls[wv][t]);
    partial[blockIdx.x * 16 + t] = m;
    partial[blockIdx.x * 16 + 8 + t] = s;
  }
}

// K3b: finalize — hms[0:8]=hmax, hms[8:16]=hsum
__global__ __launch_bounds__(TPB) void k3_final(const float* __restrict__ partial,
                                                float* __restrict__ hms) {
  int t = threadIdx.x;
  int h = t & 7;
  float m = -INFINITY, s = 0.0f;
  for (int p = t >> 3; p < NPART; p += 32)
    sm_merge(m, s, partial[p * 16 + h], partial[p * 16 + 8 + h]);
  #pragma unroll
  for (int off = 8; off <= 32; off <<= 1) {
    float mo = __shfl_xor(m, off), so = __shfl_xor(s, off);
    sm_merge(m, s, mo, so);
  }
  __shared__ float lm[4][8], ls[4][8];
  if ((t & 63) < 8) { lm[t >> 6][t & 7] = m; ls[t >> 6][t & 7] = s; }
  __syncthreads();
  if (t < 8) {
    for (int wv = 1; wv < 4; ++wv) sm_merge(m, s, lm[wv][t], ls[wv][t]);
    hms[t] = m;
    hms[8 + t] = s;
  }
}

// ---------------------------------------------------------------------------
// K5: per-node output:
//   msum = gsum@MW2 + cnt*mb2 ; agg = w(head)*msum
//   h = gelu([x,agg]@W1+b1)@W2+b2 ; out = LN(x+h)*g+b
__global__ __launch_bounds__(TPB) void k5_out(
    const float* __restrict__ x, const float* __restrict__ gsum,
    const float* __restrict__ cnt, const float* __restrict__ attn,
    const float* __restrict__ hms,
    const float* __restrict__ msg_w2, const float* __restrict__ msg_b2,
    const float* __restrict__ out_w1, const float* __restrict__ out_b1,
    const float* __restrict__ out_w2, const float* __restrict__ out_b2,
    const float* __restrict__ ln_g, const float* __restrict__ ln_b,
    float* __restrict__ out, int N) {
  __shared__ float W1[128][64];   // 32 KB
  __shared__ float W2[64][64];    // 16 KB
  __shared__ float MW2[64][64];   // 16 KB
  int t = threadIdx.x;
  for (int idx = t; idx < 128 * 64; idx += TPB) W1[idx >> 6][idx & 63] = out_w1[idx];
  for (int idx = t; idx < 64 * 64; idx += TPB) {
    W2[idx >> 6][idx & 63] = out_w2[idx];
    MW2[idx >> 6][idx & 63] = msg_w2[idx];
  }
  __syncthreads();
  int lane = t & 63, wave = t >> 6;
  float b1 = out_b1[lane], b2 = out_b2[lane], mb2 = msg_b2[lane];
  float lg = ln_g[lane], lb = ln_b[lane];
  float hm = hms[lane >> 3];
  float rs = 1.0f / hms[8 + (lane >> 3)];
  int ngroups = N >> 2;  // N divisible by 4
  for (int gid = blockIdx.x * 4 + wave; gid < ngroups; gid += gridDim.x * 4) {
    int n0 = gid * 4;
    float xr[4], g[4], msv[4];
    #pragma unroll
    for (int i = 0; i < 4; ++i) {
      int n = n0 + i;
      xr[i] = x[(size_t)n * 64 + lane];
      g[i] = gsum[(size_t)n * 64 + lane];
      msv[i] = cnt[n] * mb2;
    }
    #pragma unroll
    for (int k = 0; k < 64; ++k) {
      float w = MW2[k][lane];
      #pragma unroll
      for (int i = 0; i < 4; ++i) msv[i] = fmaf(bcastf(g[i], k), w, msv[i]);
    }
    float agg[4];
    #pragma unroll
    for (int i = 0; i < 4; ++i) {
      float a = attn[(size_t)(n0 + i) * 8 + (lane >> 3)];
      float wgt = expf(a - hm) * rs;  // exp(-inf)=0 for isolated nodes
      agg[i] = wgt * msv[i];
    }
    float t1[4] = {b1, b1, b1, b1};
    #pragma unroll
    for (int k = 0; k < 64; ++k) {
      float w0 = W1[k][lane];
      #pragma unroll
      for (int i = 0; i < 4; ++i) t1[i] = fmaf(bcastf(xr[i], k), w0, t1[i]);
    }
    #pragma unroll
    for (int k = 0; k < 64; ++k) {
      float w0 = W1[64 + k][lane];
      #pragma unroll
      for (int i = 0; i < 4; ++i) t1[i] = fmaf(bcastf(agg[i], k), w0, t1[i]);
    }
    #pragma unroll
    for (int i = 0; i < 4; ++i) t1[i] = gelu_exact(t1[i]);
    float hh[4] = {b2, b2, b2, b2};
    #pragma unroll
    for (int k = 0; k < 64; ++k) {
      float w0 = W2[k][lane];
      #pragma unroll
      for (int i = 0; i < 4; ++i) hh[i] = fmaf(bcastf(t1[i], k), w0, hh[i]);
    }
    #pragma unroll
    for (int i = 0; i < 4; ++i) {
      float y = xr[i] + hh[i];
      float s = y;
      #pragma unroll
      for (int off = 32; off >= 1; off >>= 1) s += __shfl_xor(s, off);
      float mu = s * (1.0f / 64.0f);
      float c = y - mu;
      float s2 = c * c;
      #pragma unroll
      for (int off = 32; off >= 1; off >>= 1) s2 += __shfl_xor(s2, off);
      float var = s2 * (1.0f / 64.0f);
      out[(size_t)(n0 + i) * 64 + lane] = c * rsqrtf(var + 1e-5f) * lg + lb;
    }
  }
}

// ---------------------------------------------------------------------------
extern "C" void kernel_launch(void* const* d_in, const int* in_sizes, int n_in,
                              void* d_out, int out_size, void* d_ws, size_t ws_size,
                              hipStream_t stream) {
  const float* x       = (const float*)d_in[0];
  const int*   ei      = (const int*)d_in[1];
  const float* ea      = (const float*)d_in[2];
  const float* msg_w1  = (const float*)d_in[3];
  const float* msg_b1  = (const float*)d_in[4];
  const float* msg_w2  = (const float*)d_in[5];
  const float* msg_b2  = (const float*)d_in[6];
  const float* q_w     = (const float*)d_in[7];
  const float* q_b     = (const float*)d_in[8];
  const float* kv_w    = (const float*)d_in[9];
  const float* kv_b    = (const float*)d_in[10];
  const float* out_w1  = (const float*)d_in[11];
  const float* out_b1  = (const float*)d_in[12];
  const float* out_w2  = (const float*)d_in[13];
  const float* out_b2  = (const float*)d_in[14];
  const float* ln_g    = (const float*)d_in[15];
  const float* ln_b    = (const float*)d_in[16];

  int N = in_sizes[0] / 64;
  int E = in_sizes[2] / 64;

  char* ws = (char*)d_ws;
  unsigned short* P = (unsigned short*)ws;                       // N*512 B
  float* gsum = (float*)(ws + (size_t)N * 512);                  // N*256 B
  float* attn = (float*)(ws + (size_t)N * 768);                  // N*32 B
  float* cnt  = (float*)(ws + (size_t)N * 800);                  // N*4 B
  int*   last = (int*)(ws + (size_t)N * 804);                    // N*4 B
  float* partial = (float*)(ws + (size_t)N * 808);               // NPART*64 B
  float* hms  = (float*)(ws + (size_t)N * 808 + NPART * 64);     // 64 B

  float* outp = (float*)d_out;

  k0_init<<<(N * 64 + TPB - 1) / TPB, TPB, 0, stream>>>(gsum, attn, cnt, last, N);
  k_win<<<(E + TPB - 1) / TPB, TPB, 0, stream>>>(ei, last, cnt, E);
  k1_node<<<1024, TPB, 0, stream>>>(x, msg_w1, msg_b1, q_w, q_b, kv_w, kv_b, P, N);
  k2_edge<<<2048, TPB, 0, stream>>>(ea, ei, P, gsum, msg_w1, N, E);
  k2b_attn<<<(N + 63) / 64, TPB, 0, stream>>>(ea, ei, last, P, kv_w, attn, N, E);
  k3_partial<<<NPART, TPB, 0, stream>>>(attn, partial, N * 8);
  k3_final<<<1, TPB, 0, stream>>>(partial, hms);
  k5_out<<<2048, TPB, 0, stream>>>(x, gsum, cnt, attn, hms,
                                   msg_w2, msg_b2, out_w1, out_b1,
                                   out_w2, out_b2, ln_g, ln_b, outp, N);
}